// Round 1
// baseline (369.515 us; speedup 1.0000x reference)
//
#include <hip/hip_runtime.h>

#define BB 256
#define CC 68
#define HH 64
#define WW 64

__global__ __launch_bounds__(256) void face_landmark_kernel(
    const float* __restrict__ pred_hm,   // [B,C,H,W]
    const float* __restrict__ center,    // [B,2]
    const float* __restrict__ scale,     // [B]
    float* __restrict__ out)             // [B,C,2]
{
    const int bc = blockIdx.x;           // 0 .. B*C-1
    const int b  = bc / CC;
    const int tid = threadIdx.x;

    const float* hm = pred_hm + (size_t)bc * (HH * WW);
    const float4* hm4 = (const float4*)hm;

    // Each thread scans 16 elements (4 x float4), indices ascend per-thread,
    // strict > keeps first occurrence of the max within the thread.
    float best_v = -__builtin_inff();
    int   best_i = 0;
#pragma unroll
    for (int k = 0; k < 4; ++k) {
        const int fi = tid + 256 * k;    // float4 index, coalesced across lanes
        const float4 v = hm4[fi];
        const int base = fi * 4;
        if (v.x > best_v) { best_v = v.x; best_i = base;     }
        if (v.y > best_v) { best_v = v.y; best_i = base + 1; }
        if (v.z > best_v) { best_v = v.z; best_i = base + 2; }
        if (v.w > best_v) { best_v = v.w; best_i = base + 3; }
    }

    // Wave-64 butterfly-style reduce; tie -> smaller index (first occurrence).
#pragma unroll
    for (int off = 32; off > 0; off >>= 1) {
        const float ov = __shfl_down(best_v, off, 64);
        const int   oi = __shfl_down(best_i, off, 64);
        if (ov > best_v || (ov == best_v && oi < best_i)) { best_v = ov; best_i = oi; }
    }

    __shared__ float sv[4];
    __shared__ int   si[4];
    const int wave = tid >> 6;
    const int lane = tid & 63;
    if (lane == 0) { sv[wave] = best_v; si[wave] = best_i; }
    __syncthreads();

    if (tid == 0) {
#pragma unroll
        for (int w = 1; w < 4; ++w) {
            if (sv[w] > best_v || (sv[w] == best_v && si[w] < best_i)) {
                best_v = sv[w]; best_i = si[w];
            }
        }

        const int idx = best_i;          // 0-based flat argmax
        const int iX = idx & (WW - 1);   // column
        const int iY = idx >> 6;         // row
        float px = (float)(iX + 1);      // 1-based
        float py = (float)(iY + 1);

        const bool interior = (iX > 0) && (iX < WW - 1) && (iY > 0) && (iY < HH - 1);
        if (interior) {
            // clip is a no-op when interior, but match the reference's clipped loads
            const int iXc = iX < 1 ? 1 : (iX > WW - 2 ? WW - 2 : iX);
            const int iYc = iY < 1 ? 1 : (iY > HH - 2 ? HH - 2 : iY);
            const float dx = hm[iYc * WW + iXc + 1] - hm[iYc * WW + iXc - 1];
            const float dy = hm[(iYc + 1) * WW + iXc] - hm[(iYc - 1) * WW + iXc];
            px += (dx > 0.0f) ? 0.25f : ((dx < 0.0f) ? -0.25f : 0.0f);
            py += (dy > 0.0f) ? 0.25f : ((dy < 0.0f) ? -0.25f : 0.0f);
        }
        px -= 0.5f;
        py -= 0.5f;

        const float h  = 200.0f * scale[b];
        const float hr = h * (1.0f / (float)HH);     // h / res, res = H = 64
        const float ox = px * hr + center[b * 2 + 0] - 0.5f * h;
        const float oy = py * hr + center[b * 2 + 1] - 0.5f * h;

        ((float2*)out)[bc] = make_float2(ox, oy);
    }
}

extern "C" void kernel_launch(void* const* d_in, const int* in_sizes, int n_in,
                              void* d_out, int out_size, void* d_ws, size_t ws_size,
                              hipStream_t stream) {
    const float* pred_hm = (const float*)d_in[0];   // [256,68,64,64] f32
    const float* center  = (const float*)d_in[1];   // [256,2] f32
    const float* scale   = (const float*)d_in[2];   // [256] f32
    float* out = (float*)d_out;                     // [256,68,2] f32

    face_landmark_kernel<<<dim3(BB * CC), dim3(256), 0, stream>>>(
        pred_hm, center, scale, out);
}